// Round 1
// baseline (602.082 us; speedup 1.0000x reference)
//
#include <hip/hip_runtime.h>
#include <math.h>

#define N 1024
#define DIM 128
#define NM1 1023
#define LAMB 0.9f
#define INV2SIG2 (1.0f / 450.0f)   // 0.5 / sigma^2, sigma=15
#define ITERS 160

// ---------------- K0: zero-init u and total ----------------
__global__ void k_init(float* __restrict__ u, float* __restrict__ total) {
    int t = blockIdx.x * blockDim.x + threadIdx.x;
    if (t < N) total[t] = 0.f;
    if (t < N) u[t] = 0.f;
}

// ---------------- K1: fused 4-layer MLP ----------------
// applies (w2,b2),(w3,b3),(w4,b4) -> g (=f4), then (w1,b1) -> x
// also fn2[j]=||g_j||^2, mag[j]=||x_j||^2
#define ROWS 16
__global__ __launch_bounds__(256) void k_mlp(
    const float* __restrict__ f,
    const float* __restrict__ w1, const float* __restrict__ b1,
    const float* __restrict__ w2, const float* __restrict__ b2,
    const float* __restrict__ w3, const float* __restrict__ b3,
    const float* __restrict__ w4, const float* __restrict__ b4,
    float* __restrict__ g, float* __restrict__ x,
    float* __restrict__ fn2, float* __restrict__ mag)
{
    __shared__ float tbuf[2][ROWS][DIM];
    __shared__ float wch[DIM][33];   // 32-wide k-chunk of weights, padded
    __shared__ float bsh[DIM];
    const int t = threadIdx.x;
    const int row0 = blockIdx.x * ROWS;
    const float* Ws[4] = {w2, w3, w4, w1};
    const float* Bs[4] = {b2, b3, b4, b1};

    for (int idx = t; idx < ROWS * DIM; idx += 256)
        tbuf[0][idx >> 7][idx & 127] = f[(row0 + (idx >> 7)) * DIM + (idx & 127)];

    int cur = 0;
    const int o = t & 127;       // fixed output column per thread
    const int rbase = t >> 7;    // 0 or 1

    for (int L = 0; L < 4; ++L) {
        const float* w = Ws[L];
        if (t < DIM) bsh[t] = Bs[L][t];
        float acc[8];
        #pragma unroll
        for (int s = 0; s < 8; ++s) acc[s] = 0.f;

        for (int kc = 0; kc < 4; ++kc) {
            __syncthreads();
            for (int idx = t; idx < DIM * 32; idx += 256) {
                int oo = idx >> 5, kk = idx & 31;
                wch[oo][kk] = w[oo * DIM + kc * 32 + kk];
            }
            __syncthreads();
            #pragma unroll
            for (int s = 0; s < 8; ++s) {
                int r = rbase + 2 * s;
                #pragma unroll
                for (int kk = 0; kk < 32; ++kk)
                    acc[s] += tbuf[cur][r][kc * 32 + kk] * wch[o][kk];
            }
        }
        __syncthreads();
        #pragma unroll
        for (int s = 0; s < 8; ++s)
            tbuf[cur ^ 1][rbase + 2 * s][o] = acc[s] + bsh[o];
        cur ^= 1;
        __syncthreads();

        if (L == 2) {  // f4 ready
            for (int idx = t; idx < ROWS * DIM; idx += 256)
                g[(row0 + (idx >> 7)) * DIM + (idx & 127)] = tbuf[cur][idx >> 7][idx & 127];
            if (t < ROWS) {
                float s2 = 0.f;
                for (int k = 0; k < DIM; ++k) { float vv = tbuf[cur][t][k]; s2 += vv * vv; }
                fn2[row0 + t] = s2;
            }
        }
    }
    // x ready
    for (int idx = t; idx < ROWS * DIM; idx += 256)
        x[(row0 + (idx >> 7)) * DIM + (idx & 127)] = tbuf[cur][idx >> 7][idx & 127];
    if (t < ROWS) {
        float s2 = 0.f;
        for (int k = 0; k < DIM; ++k) { float vv = tbuf[cur][t][k]; s2 += vv * vv; }
        mag[row0 + t] = s2;
    }
}

// ---------------- K2: A[i,j] = exp(-(S-1)^2 * fn2_j / (2 sig^2)), row sums ----------------
__global__ __launch_bounds__(256) void k_affinity(
    const float* __restrict__ x, const float* __restrict__ mag,
    const float* __restrict__ fn2, float* __restrict__ A,
    float* __restrict__ total)
{
    __shared__ float xi[32][129];
    __shared__ float xj[32][129];
    __shared__ float rowpart[32];
    const int t = threadIdx.x;
    const int i0 = blockIdx.y * 32, j0 = blockIdx.x * 32;

    for (int idx = t; idx < 32 * DIM; idx += 256) {
        int r = idx >> 7, k = idx & 127;
        xi[r][k] = x[(i0 + r) * DIM + k];
        xj[r][k] = x[(j0 + r) * DIM + k];
    }
    __syncthreads();

    const int jj = t & 31;
    const int ibase = t >> 5;       // 0..7, lanes 0..31 of each wave share it
    const int lane = t & 63;
    const float magj = mag[j0 + jj];
    const float fnj  = fn2[j0 + jj];

    #pragma unroll
    for (int s = 0; s < 4; ++s) {
        int ii = ibase + 8 * s;
        float acc = 0.f;
        #pragma unroll 16
        for (int k = 0; k < DIM; ++k) acc += xi[ii][k] * xj[jj][k];
        int gi = i0 + ii, gj = j0 + jj;
        float a;
        if (gi == gj) {
            a = 1.0f;
        } else {
            float Sv = acc / magj - 1.0f;
            a = expf(-(Sv * Sv) * fnj * INV2SIG2);
        }
        A[gi * N + gj] = a;
        float c = (gi == gj) ? 0.f : a;
        // reduce over the 32-lane half-wave (all share ii)
        #pragma unroll
        for (int off = 16; off >= 1; off >>= 1) c += __shfl_xor(c, off, 64);
        if ((lane & 31) == 0) rowpart[ii] = c;   // unique (ii per half-wave per s)
        // accumulate the 4 s-slots: rowpart indices are unique across all writers
        if ((lane & 31) == 0 && s == 3) {} // no-op, keep structure simple
        __syncthreads();
        if (t < 32 && s == 3) {} // placeholder
        __syncthreads();
        if ((lane & 31) == 0) atomicAdd(&total[gi], c);
    }
}

// ---------------- K3: normalize in place: T = A / max(total,1e-10), diag 0 ----------------
__global__ __launch_bounds__(256) void k_norm(float* __restrict__ A,
                                              const float* __restrict__ total)
{
    int gid = blockIdx.x * blockDim.x + threadIdx.x;   // one float4 each
    int i = (gid << 2) >> 10;
    float tt = fmaxf(total[i], 1e-10f);
    float4 v = ((float4*)A)[gid];
    int j0 = (gid << 2) & 1023;
    v.x = (i == j0 + 0) ? 0.f : v.x / tt;
    v.y = (i == j0 + 1) ? 0.f : v.y / tt;
    v.z = (i == j0 + 2) ? 0.f : v.z / tt;
    v.w = (i == j0 + 3) ? 0.f : v.w / tt;
    ((float4*)A)[gid] = v;
}

// ---------------- K4: v = P0 + lambda * Tm * u ----------------
__global__ __launch_bounds__(256) void k_matvec(const float* __restrict__ T,
                                                const float* __restrict__ u,
                                                float* __restrict__ v)
{
    int wid = (blockIdx.x * 256 + threadIdx.x) >> 6;
    int lane = threadIdx.x & 63;
    if (wid >= NM1) return;
    const float* row = T + (wid + 1) * N + 1;   // Tm row wid
    float acc = 0.f;
    #pragma unroll
    for (int j = 0; j < 15; ++j) {
        int c = lane + 64 * j;                  // <= 959, always valid
        acc += row[c] * u[c];
    }
    {
        int c = lane + 960;
        if (c < NM1) acc += row[c] * u[c];
    }
    #pragma unroll
    for (int off = 32; off >= 1; off >>= 1) acc += __shfl_down(acc, off, 64);
    if (lane == 0) v[wid] = T[wid + 1] + LAMB * acc;   // T[0][wid+1] = P0[wid]
}

// ---------------- K5: epilogue: P=(1-l)u; P-=mean; relu*100; softmax ----------------
__global__ __launch_bounds__(1024) void k_epilogue(const float* __restrict__ uf,
                                                   float* __restrict__ out)
{
    __shared__ float red[16];
    __shared__ float bval;
    const int t = threadIdx.x;
    const int wv = t >> 6, lane = t & 63;
    const bool valid = t < NM1;
    float P = valid ? 0.1f * uf[t] : 0.f;

    // mean
    float s = P;
    #pragma unroll
    for (int off = 32; off >= 1; off >>= 1) s += __shfl_down(s, off, 64);
    if (lane == 0) red[wv] = s;
    __syncthreads();
    if (t < 64) {
        float s2 = (t < 16) ? red[t] : 0.f;
        #pragma unroll
        for (int off = 8; off >= 1; off >>= 1) s2 += __shfl_down(s2, off, 64);
        if (t == 0) bval = s2 / 1023.0f;
    }
    __syncthreads();
    float mean = bval;
    P = valid ? fmaxf(P - mean, 0.f) * 100.f : 0.f;

    // max
    __syncthreads();
    float m = P;   // >= 0 for all, invalid lanes contribute 0 (safe: true max >= 0)
    #pragma unroll
    for (int off = 32; off >= 1; off >>= 1) m = fmaxf(m, __shfl_down(m, off, 64));
    if (lane == 0) red[wv] = m;
    __syncthreads();
    if (t < 64) {
        float m2 = (t < 16) ? red[t] : 0.f;
        #pragma unroll
        for (int off = 8; off >= 1; off >>= 1) m2 = fmaxf(m2, __shfl_down(m2, off, 64));
        if (t == 0) bval = m2;
    }
    __syncthreads();
    float gmax = bval;
    float e = valid ? expf(P - gmax) : 0.f;

    __syncthreads();
    float s3 = e;
    #pragma unroll
    for (int off = 32; off >= 1; off >>= 1) s3 += __shfl_down(s3, off, 64);
    if (lane == 0) red[wv] = s3;
    __syncthreads();
    if (t < 64) {
        float s4 = (t < 16) ? red[t] : 0.f;
        #pragma unroll
        for (int off = 8; off >= 1; off >>= 1) s4 += __shfl_down(s4, off, 64);
        if (t == 0) bval = s4;
    }
    __syncthreads();
    if (valid) out[t] = e / bval;
}

extern "C" void kernel_launch(void* const* d_in, const int* in_sizes, int n_in,
                              void* d_out, int out_size, void* d_ws, size_t ws_size,
                              hipStream_t stream) {
    const float* f  = (const float*)d_in[0];
    const float* w1 = (const float*)d_in[1];
    const float* b1 = (const float*)d_in[2];
    const float* w2 = (const float*)d_in[3];
    const float* b2 = (const float*)d_in[4];
    const float* w3 = (const float*)d_in[5];
    const float* b3 = (const float*)d_in[6];
    const float* w4 = (const float*)d_in[7];
    const float* b4 = (const float*)d_in[8];
    float* ws = (float*)d_ws;

    float* g     = ws;                 // 1024*128
    float* x     = ws + 131072;        // 1024*128
    float* fn2   = ws + 262144;        // 1024
    float* mag   = ws + 263168;        // 1024
    float* total = ws + 264192;        // 1024
    float* u     = ws + 265216;        // 1024
    float* v     = ws + 266240;        // 1024
    float* T     = ws + 267264;        // 1024*1024
    float* out   = (float*)d_out;

    k_init<<<4, 256, 0, stream>>>(u, total);
    k_mlp<<<64, 256, 0, stream>>>(f, w1, b1, w2, b2, w3, b3, w4, b4, g, x, fn2, mag);
    k_affinity<<<dim3(32, 32), 256, 0, stream>>>(x, mag, fn2, T, total);
    k_norm<<<1024, 256, 0, stream>>>(T, total);

    float* cu = u; float* cv = v;
    for (int it = 0; it < ITERS; ++it) {
        k_matvec<<<256, 256, 0, stream>>>(T, cu, cv);
        float* tmp = cu; cu = cv; cv = tmp;
    }
    k_epilogue<<<1, 1024, 0, stream>>>(cu, out);
}

// Round 2
// 270.268 us; speedup vs baseline: 2.2277x; 2.2277x over previous
//
#include <hip/hip_runtime.h>
#include <math.h>

#define N 1024
#define DIM 128
#define NM1 1023
#define LAMB 0.9f
#define INV2SIG2 (1.0f / 450.0f)   // 0.5 / sigma^2, sigma=15
#define ITERS 64                   // 0.9^64 ~ 1.2e-3; out err ~1e-6 << 1.95e-5 threshold

// ---------------- K0: zero-init accumulator arrays ----------------
__global__ void k_init(float* __restrict__ z) {
    int t = blockIdx.x * blockDim.x + threadIdx.x;   // 4096 threads: u, total, fn2, mag
    z[t] = 0.f;
}

// ---------------- KS: small compose matmul: C = A*B (128x128), bout = A*bin + d --------
__global__ __launch_bounds__(256) void k_small(
    const float* __restrict__ A, const float* __restrict__ B,
    const float* __restrict__ bin, const float* __restrict__ dbias,
    float* __restrict__ C, float* __restrict__ bout)
{
    const int b = blockIdx.x;
    const int t = threadIdx.x;
    if (b < 64) {
        const int h = t >> 7, j = t & 127;
        const int i = 2 * b + h;
        float acc = 0.f;
        #pragma unroll 8
        for (int k = 0; k < 128; ++k)
            acc += A[i * 128 + k] * B[k * 128 + j];
        C[i * 128 + j] = acc;
    } else {
        if (t < 128) {
            float acc = dbias[t];
            #pragma unroll 8
            for (int k = 0; k < 128; ++k)
                acc += A[t * 128 + k] * bin[k];
            bout[t] = acc;
        }
    }
}

// ---------------- K1: Y = f @ Wboth^T + bboth; store x-part; accumulate fn2/mag ------
// Wboth row-major [256][128]: rows 0-127 = G (f4 weights), 128-255 = Xw (x weights)
__global__ __launch_bounds__(256) void k_gemm(
    const float* __restrict__ f, const float* __restrict__ Wb,
    const float* __restrict__ bb,
    float* __restrict__ x, float* __restrict__ fn2, float* __restrict__ mag)
{
    __shared__ float4 fl4[64][33];
    __shared__ float4 wl4[64][33];
    __shared__ float bsh[64];
    const int t = threadIdx.x;
    const int row0 = blockIdx.y * 64;   // 0..960
    const int col0 = blockIdx.x * 64;   // 0..192 over N=256
    const float4* F4 = (const float4*)f;
    const float4* W4p = (const float4*)Wb;

    #pragma unroll
    for (int s = 0; s < 8; ++s) {
        int idx = t + 256 * s;
        int r = idx >> 5, k4 = idx & 31;
        fl4[r][k4] = F4[(row0 + r) * 32 + k4];
        wl4[r][k4] = W4p[(col0 + r) * 32 + k4];
    }
    if (t < 64) bsh[t] = bb[col0 + t];
    __syncthreads();

    const int tx = t & 15, ty = t >> 4;
    float acc[4][4];
    #pragma unroll
    for (int i = 0; i < 4; ++i)
        #pragma unroll
        for (int j = 0; j < 4; ++j) acc[i][j] = 0.f;

    for (int k4 = 0; k4 < 32; ++k4) {
        float4 fa[4], wv[4];
        #pragma unroll
        for (int i = 0; i < 4; ++i) fa[i] = fl4[ty + 16 * i][k4];
        #pragma unroll
        for (int j = 0; j < 4; ++j) wv[j] = wl4[tx + 16 * j][k4];
        #pragma unroll
        for (int i = 0; i < 4; ++i)
            #pragma unroll
            for (int j = 0; j < 4; ++j)
                acc[i][j] += fa[i].x * wv[j].x + fa[i].y * wv[j].y
                           + fa[i].z * wv[j].z + fa[i].w * wv[j].w;
    }

    const bool isg = (col0 < 128);
    #pragma unroll
    for (int i = 0; i < 4; ++i) {
        int gr = row0 + ty + 16 * i;
        float ss = 0.f;
        #pragma unroll
        for (int j = 0; j < 4; ++j) {
            int c = tx + 16 * j;
            float yv = acc[i][j] + bsh[c];
            ss += yv * yv;
            if (!isg) x[gr * 128 + (col0 - 128) + c] = yv;
        }
        #pragma unroll
        for (int off = 1; off < 16; off <<= 1) ss += __shfl_xor(ss, off, 64);
        if (tx == 0) atomicAdd(isg ? &fn2[gr] : &mag[gr], ss);
    }
}

// ---------------- K2: A[i,j] = exp(-(S-1)^2 fn2_j /(2 sig^2)) (diag=0), row totals ----
__global__ __launch_bounds__(256) void k_aff(
    const float* __restrict__ x, const float* __restrict__ mag,
    const float* __restrict__ fn2, float* __restrict__ A,
    float* __restrict__ total)
{
    __shared__ float4 xi4[64][33];
    __shared__ float4 xj4[64][33];
    __shared__ float mg[64], fn[64];
    const int t = threadIdx.x;
    const int i0 = blockIdx.y * 64, j0 = blockIdx.x * 64;
    const float4* X4 = (const float4*)x;

    #pragma unroll
    for (int s = 0; s < 8; ++s) {
        int idx = t + 256 * s;
        int r = idx >> 5, k4 = idx & 31;
        xi4[r][k4] = X4[(i0 + r) * 32 + k4];
        xj4[r][k4] = X4[(j0 + r) * 32 + k4];
    }
    if (t < 64) { mg[t] = mag[j0 + t]; fn[t] = fn2[j0 + t]; }
    __syncthreads();

    const int tx = t & 15, ty = t >> 4;
    float acc[4][4];
    #pragma unroll
    for (int i = 0; i < 4; ++i)
        #pragma unroll
        for (int j = 0; j < 4; ++j) acc[i][j] = 0.f;

    for (int k4 = 0; k4 < 32; ++k4) {
        float4 xa[4], xb[4];
        #pragma unroll
        for (int i = 0; i < 4; ++i) xa[i] = xi4[ty + 16 * i][k4];
        #pragma unroll
        for (int j = 0; j < 4; ++j) xb[j] = xj4[tx + 16 * j][k4];
        #pragma unroll
        for (int i = 0; i < 4; ++i)
            #pragma unroll
            for (int j = 0; j < 4; ++j)
                acc[i][j] += xa[i].x * xb[j].x + xa[i].y * xb[j].y
                           + xa[i].z * xb[j].z + xa[i].w * xb[j].w;
    }

    float rmag[4], fnj[4];
    #pragma unroll
    for (int j = 0; j < 4; ++j) {
        rmag[j] = 1.0f / mg[tx + 16 * j];
        fnj[j]  = fn[tx + 16 * j] * INV2SIG2;
    }

    #pragma unroll
    for (int i = 0; i < 4; ++i) {
        int gi = i0 + ty + 16 * i;
        float rs = 0.f;
        #pragma unroll
        for (int j = 0; j < 4; ++j) {
            int gj = j0 + tx + 16 * j;
            float Sm1 = acc[i][j] * rmag[j] - 1.0f;
            float a = (gi == gj) ? 0.f : expf(-(Sm1 * Sm1) * fnj[j]);
            A[gi * N + gj] = a;
            rs += a;
        }
        #pragma unroll
        for (int off = 1; off < 16; off <<= 1) rs += __shfl_xor(rs, off, 64);
        if (tx == 0) atomicAdd(&total[gi], rs);
    }
}

// ---------------- K4: v_ext[r] = P0[r-1] + lambda*(Tm u)[r-1]; v_ext[0]=0 ------------
// T folded: T[i][j] = A[i][j]/total[i]; u_ext[0]==0 makes col 0 harmless.
__global__ __launch_bounds__(256) void k_mv(const float* __restrict__ A,
                                            const float* __restrict__ total,
                                            const float* __restrict__ u,
                                            float* __restrict__ v)
{
    const int gid = blockIdx.x * 256 + threadIdx.x;
    const int r = gid >> 6;
    const int lane = threadIdx.x & 63;
    if (r == 0) { if (lane == 0) v[0] = 0.f; return; }
    const float4* Ar = (const float4*)(A + r * N);
    const float4* U4 = (const float4*)u;
    float acc = 0.f;
    #pragma unroll
    for (int p = 0; p < 4; ++p) {
        float4 av = Ar[lane + 64 * p];
        float4 uv = U4[lane + 64 * p];
        acc += av.x * uv.x + av.y * uv.y + av.z * uv.z + av.w * uv.w;
    }
    #pragma unroll
    for (int off = 32; off >= 1; off >>= 1) acc += __shfl_xor(acc, off, 64);
    if (lane == 0) {
        float rt0 = 1.0f / fmaxf(total[0], 1e-10f);
        float rtr = 1.0f / fmaxf(total[r], 1e-10f);
        v[r] = A[r] * rt0 + LAMB * rtr * acc;   // A[0*N+r] = P0 numerator
    }
}

// ---------------- K5: epilogue: P=0.1*u; center; relu*100; softmax -------------------
__global__ __launch_bounds__(1024) void k_epilogue(const float* __restrict__ uf,
                                                   float* __restrict__ out)
{
    __shared__ float red[16];
    __shared__ float bval;
    const int t = threadIdx.x;
    const int wv = t >> 6, lane = t & 63;
    const bool valid = t < NM1;
    float P = valid ? 0.1f * uf[t + 1] : 0.f;

    float s = P;
    #pragma unroll
    for (int off = 32; off >= 1; off >>= 1) s += __shfl_down(s, off, 64);
    if (lane == 0) red[wv] = s;
    __syncthreads();
    if (t < 64) {
        float s2 = (t < 16) ? red[t] : 0.f;
        #pragma unroll
        for (int off = 8; off >= 1; off >>= 1) s2 += __shfl_down(s2, off, 64);
        if (t == 0) bval = s2 / 1023.0f;
    }
    __syncthreads();
    float mean = bval;
    P = valid ? fmaxf(P - mean, 0.f) * 100.f : 0.f;

    __syncthreads();
    float m = P;
    #pragma unroll
    for (int off = 32; off >= 1; off >>= 1) m = fmaxf(m, __shfl_down(m, off, 64));
    if (lane == 0) red[wv] = m;
    __syncthreads();
    if (t < 64) {
        float m2 = (t < 16) ? red[t] : 0.f;
        #pragma unroll
        for (int off = 8; off >= 1; off >>= 1) m2 = fmaxf(m2, __shfl_down(m2, off, 64));
        if (t == 0) bval = m2;
    }
    __syncthreads();
    float gmax = bval;
    float e = valid ? expf(P - gmax) : 0.f;

    __syncthreads();
    float s3 = e;
    #pragma unroll
    for (int off = 32; off >= 1; off >>= 1) s3 += __shfl_down(s3, off, 64);
    if (lane == 0) red[wv] = s3;
    __syncthreads();
    if (t < 64) {
        float s4 = (t < 16) ? red[t] : 0.f;
        #pragma unroll
        for (int off = 8; off >= 1; off >>= 1) s4 += __shfl_down(s4, off, 64);
        if (t == 0) bval = s4;
    }
    __syncthreads();
    if (valid) out[t] = e / bval;
}

extern "C" void kernel_launch(void* const* d_in, const int* in_sizes, int n_in,
                              void* d_out, int out_size, void* d_ws, size_t ws_size,
                              hipStream_t stream) {
    const float* f  = (const float*)d_in[0];
    const float* w1 = (const float*)d_in[1];
    const float* b1 = (const float*)d_in[2];
    const float* w2 = (const float*)d_in[3];
    const float* b2 = (const float*)d_in[4];
    const float* w3 = (const float*)d_in[5];
    const float* b3 = (const float*)d_in[6];
    const float* w4 = (const float*)d_in[7];
    const float* b4 = (const float*)d_in[8];
    float* ws = (float*)d_ws;

    float* A     = ws;                  // 1024*1024
    float* x     = ws + 1048576;        // 1024*128
    float* C1    = ws + 1179648;        // 128*128
    float* Wboth = ws + 1196032;        // 256*128
    float* bboth = ws + 1228800;        // 256
    float* beta1 = ws + 1229056;        // 128
    float* fn2   = ws + 1229184;        // 1024
    float* mag   = ws + 1230208;        // 1024
    float* total = ws + 1231232;        // 1024
    float* u     = ws + 1232256;        // 1024 (u_ext)
    float* v     = ws + 1233280;        // 1024 (v_ext)
    float* out   = (float*)d_out;

    // zero: fn2, mag, total, u (contiguous 4096 floats starting at fn2... not contiguous
    // with u; zero fn2..v span = 1229184..1234304 = 5120 floats)
    k_init<<<20, 256, 0, stream>>>(ws + 1229184);   // fn2,mag,total,u,v all zeroed

    // Compose: C1 = W3*W2, beta1 = W3*b2+b3; G = W4*C1 -> Wboth[0:128], bg -> bboth[0:128];
    //          Xw = W1*G -> Wboth[128:256], bx -> bboth[128:256]
    k_small<<<65, 256, 0, stream>>>(w3, w2, b2, b3, C1, beta1);
    k_small<<<65, 256, 0, stream>>>(w4, C1, beta1, b4, Wboth, bboth);
    k_small<<<65, 256, 0, stream>>>(w1, Wboth, bboth, b1, Wboth + 16384, bboth + 128);

    k_gemm<<<dim3(4, 16), 256, 0, stream>>>(f, Wboth, bboth, x, fn2, mag);
    k_aff<<<dim3(16, 16), 256, 0, stream>>>(x, mag, fn2, A, total);

    float* cu = u; float* cv = v;
    for (int it = 0; it < ITERS; ++it) {
        k_mv<<<256, 256, 0, stream>>>(A, total, cu, cv);
        float* tmp = cu; cu = cv; cv = tmp;
    }
    k_epilogue<<<1, 1024, 0, stream>>>(cu, out);
}

// Round 3
// 208.678 us; speedup vs baseline: 2.8852x; 1.2951x over previous
//
#include <hip/hip_runtime.h>
#include <math.h>

#define N 1024
#define NM1 1023
#define DIM 128
#define LAMB 0.9f
#define INV2SIG2 (1.0f / 450.0f)   // 0.5 / sigma^2, sigma=15

typedef short v8s __attribute__((ext_vector_type(8)));
typedef float v4f __attribute__((ext_vector_type(4)));

__device__ __forceinline__ unsigned short f2bf(float x) {   // RNE float->bf16
    unsigned int u = __float_as_uint(x);
    u += 0x7FFFu + ((u >> 16) & 1u);
    return (unsigned short)(u >> 16);
}
__device__ __forceinline__ float bf2f(unsigned short h) {
    return __uint_as_float(((unsigned int)h) << 16);
}

// ---------------- K0: zero-init fn2/mag/total (3072 floats) ----------------
__global__ void k_init(float* __restrict__ z) {
    z[blockIdx.x * blockDim.x + threadIdx.x] = 0.f;
}

// ---------------- KS: compose matmul C = A*B (128x128); bout = A*bin + d ----
__global__ __launch_bounds__(256) void k_small(
    const float* __restrict__ A, const float* __restrict__ B,
    const float* __restrict__ bin, const float* __restrict__ dbias,
    float* __restrict__ C, float* __restrict__ bout)
{
    const int b = blockIdx.x;
    const int t = threadIdx.x;
    if (b < 64) {
        const int h = t >> 7, j = t & 127;
        const int i = 2 * b + h;
        float acc = 0.f;
        #pragma unroll 8
        for (int k = 0; k < 128; ++k)
            acc += A[i * 128 + k] * B[k * 128 + j];
        C[i * 128 + j] = acc;
    } else {
        if (t < 128) {
            float acc = dbias[t];
            #pragma unroll 8
            for (int k = 0; k < 128; ++k)
                acc += A[t * 128 + k] * bin[k];
            bout[t] = acc;
        }
    }
}

// ---------------- K1: Y = f @ Wboth^T + bboth; xb (bf16) + fn2/mag ----------
__global__ __launch_bounds__(256) void k_gemm(
    const float* __restrict__ f, const float* __restrict__ Wb,
    const float* __restrict__ bb,
    unsigned short* __restrict__ xb, float* __restrict__ fn2, float* __restrict__ mag)
{
    __shared__ float4 fl4[64][33];
    __shared__ float4 wl4[64][33];
    __shared__ float bsh[64];
    const int t = threadIdx.x;
    const int row0 = blockIdx.y * 64;
    const int col0 = blockIdx.x * 64;   // over 256 outputs
    const float4* F4 = (const float4*)f;
    const float4* W4p = (const float4*)Wb;

    #pragma unroll
    for (int s = 0; s < 8; ++s) {
        int idx = t + 256 * s;
        int r = idx >> 5, k4 = idx & 31;
        fl4[r][k4] = F4[(row0 + r) * 32 + k4];
        wl4[r][k4] = W4p[(col0 + r) * 32 + k4];
    }
    if (t < 64) bsh[t] = bb[col0 + t];
    __syncthreads();

    const int tx = t & 15, ty = t >> 4;
    float acc[4][4];
    #pragma unroll
    for (int i = 0; i < 4; ++i)
        #pragma unroll
        for (int j = 0; j < 4; ++j) acc[i][j] = 0.f;

    for (int k4 = 0; k4 < 32; ++k4) {
        float4 fa[4], wv[4];
        #pragma unroll
        for (int i = 0; i < 4; ++i) fa[i] = fl4[ty + 16 * i][k4];
        #pragma unroll
        for (int j = 0; j < 4; ++j) wv[j] = wl4[tx + 16 * j][k4];
        #pragma unroll
        for (int i = 0; i < 4; ++i)
            #pragma unroll
            for (int j = 0; j < 4; ++j)
                acc[i][j] += fa[i].x * wv[j].x + fa[i].y * wv[j].y
                           + fa[i].z * wv[j].z + fa[i].w * wv[j].w;
    }

    const bool isg = (col0 < 128);
    #pragma unroll
    for (int i = 0; i < 4; ++i) {
        int gr = row0 + ty + 16 * i;
        float ss = 0.f;
        #pragma unroll
        for (int j = 0; j < 4; ++j) {
            int c = tx + 16 * j;
            float yv = acc[i][j] + bsh[c];
            ss += yv * yv;
            if (!isg) xb[gr * DIM + (col0 - 128) + c] = f2bf(yv);
        }
        #pragma unroll
        for (int off = 1; off < 16; off <<= 1) ss += __shfl_xor(ss, off, 64);
        if (tx == 0) atomicAdd(isg ? &fn2[gr] : &mag[gr], ss);
    }
}

// ---------------- K2: MFMA affinity A = exp(-(S-1)^2 fn2_j/450), diag 0, totals ----
// C = Xb * Xb^T : both operands are ROWS of Xb (no transpose needed).
__global__ __launch_bounds__(512) void k_aff(
    const unsigned short* __restrict__ xb, const float* __restrict__ mag,
    const float* __restrict__ fn2, float* __restrict__ A,
    float* __restrict__ total)
{
    const int t = threadIdx.x;
    const int wave = t >> 6, lane = t & 63;
    const int wm = wave >> 1, wn = wave & 1;
    const int l15 = lane & 15, quad = lane >> 4;
    const int i0 = blockIdx.y * 64, j0 = blockIdx.x * 64;

    const unsigned short* ar  = xb + (i0 + wm * 16 + l15) * DIM + quad * 8;
    const unsigned short* b0r = xb + (j0 + wn * 32 + l15) * DIM + quad * 8;
    const unsigned short* b1r = b0r + 16 * DIM;

    v4f acc0 = {0.f, 0.f, 0.f, 0.f}, acc1 = {0.f, 0.f, 0.f, 0.f};
    #pragma unroll
    for (int kc = 0; kc < 4; ++kc) {
        v8s a  = *(const v8s*)(ar  + kc * 32);
        v8s b0 = *(const v8s*)(b0r + kc * 32);
        v8s b1 = *(const v8s*)(b1r + kc * 32);
        acc0 = __builtin_amdgcn_mfma_f32_16x16x32_bf16(a, b0, acc0, 0, 0, 0);
        acc1 = __builtin_amdgcn_mfma_f32_16x16x32_bf16(a, b1, acc1, 0, 0, 0);
    }

    const int gj0 = j0 + wn * 32 + l15;
    const int gj1 = gj0 + 16;
    const float rm0 = 1.0f / mag[gj0], rm1 = 1.0f / mag[gj1];
    const float fj0 = fn2[gj0] * INV2SIG2, fj1 = fn2[gj1] * INV2SIG2;

    #pragma unroll
    for (int reg = 0; reg < 4; ++reg) {
        int gi = i0 + wm * 16 + quad * 4 + reg;
        float S0 = acc0[reg] * rm0 - 1.0f;
        float S1 = acc1[reg] * rm1 - 1.0f;
        float a0 = (gi == gj0) ? 0.f : __expf(-(S0 * S0) * fj0);
        float a1 = (gi == gj1) ? 0.f : __expf(-(S1 * S1) * fj1);
        A[gi * N + gj0] = a0;
        A[gi * N + gj1] = a1;
        float s = a0 + a1;
        #pragma unroll
        for (int off = 1; off < 16; off <<= 1) s += __shfl_xor(s, off, 64);
        if (l15 == 0) atomicAdd(&total[gi], s);
    }
}

// ---------------- K3: Bb = bf16(lambda * A[i][j]/total_i), row0/col0 = 0; + BbT; + P0f
__global__ __launch_bounds__(256) void k_makeB(
    const float* __restrict__ A, const float* __restrict__ total,
    unsigned short* __restrict__ Bb, unsigned short* __restrict__ BbT,
    float* __restrict__ P0f)
{
    __shared__ unsigned short Lt[64][65];
    const int t = threadIdx.x;
    const int i0 = blockIdx.y * 64, j0 = blockIdx.x * 64;
    const int r = t >> 2, c0 = (t & 3) * 16;
    const int gi = i0 + r;
    const float rt = LAMB / fmaxf(total[gi], 1e-10f);

    const float4* Ar = (const float4*)(A + gi * N + j0 + c0);
    unsigned short ob[16];
    #pragma unroll
    for (int q = 0; q < 4; ++q) {
        float4 av = Ar[q];
        float vv[4] = {av.x, av.y, av.z, av.w};
        #pragma unroll
        for (int e = 0; e < 4; ++e) {
            int gj = j0 + c0 + 4 * q + e;
            float val = (gi >= 1 && gj >= 1) ? vv[e] * rt : 0.f;
            ob[4 * q + e] = f2bf(val);
        }
    }
    uint4 p0, p1;
    unsigned short* pp0 = (unsigned short*)&p0;
    unsigned short* pp1 = (unsigned short*)&p1;
    #pragma unroll
    for (int e = 0; e < 8; ++e) { pp0[e] = ob[e]; pp1[e] = ob[8 + e]; }
    *(uint4*)(Bb + gi * N + j0 + c0)     = p0;
    *(uint4*)(Bb + gi * N + j0 + c0 + 8) = p1;
    #pragma unroll
    for (int e = 0; e < 16; ++e) Lt[r][c0 + e] = ob[e];

    if (blockIdx.y == 0 && t < 64) {
        int gj = j0 + t;
        P0f[gj] = (gj == 0) ? 0.f : A[gj] / fmaxf(total[0], 1e-10f);
    }
    __syncthreads();

    const int c = t >> 2, r0 = (t & 3) * 16;
    uint4 q0, q1;
    unsigned short* qq0 = (unsigned short*)&q0;
    unsigned short* qq1 = (unsigned short*)&q1;
    #pragma unroll
    for (int e = 0; e < 8; ++e) { qq0[e] = Lt[r0 + e][c]; qq1[e] = Lt[r0 + 8 + e][c]; }
    *(uint4*)(BbT + (j0 + c) * N + i0 + r0)     = q0;
    *(uint4*)(BbT + (j0 + c) * N + i0 + r0 + 8) = q1;
}

// ---------------- K4: bf16 MFMA squaring C = M*M (+ CT) ----------------
// A-operand: rows of M; B-operand: rows of MT. No LDS in the K-loop.
__global__ __launch_bounds__(512) void k_sq(
    const unsigned short* __restrict__ M, const unsigned short* __restrict__ MT,
    unsigned short* __restrict__ C, unsigned short* __restrict__ CT)
{
    __shared__ unsigned short Lt[64][65];
    const int t = threadIdx.x;
    const int wave = t >> 6, lane = t & 63;
    const int wm = wave >> 1, wn = wave & 1;
    const int l15 = lane & 15, quad = lane >> 4;
    const int i0 = blockIdx.y * 64, j0 = blockIdx.x * 64;

    const unsigned short* ar  = M  + (i0 + wm * 16 + l15) * N + quad * 8;
    const unsigned short* b0r = MT + (j0 + wn * 32 + l15) * N + quad * 8;
    const unsigned short* b1r = b0r + 16 * N;

    v4f acc0 = {0.f, 0.f, 0.f, 0.f}, acc1 = {0.f, 0.f, 0.f, 0.f};
    v8s a  = *(const v8s*)ar;
    v8s b0 = *(const v8s*)b0r;
    v8s b1 = *(const v8s*)b1r;
    for (int kc = 0; kc < 32; ++kc) {
        v8s an = a, b0n = b0, b1n = b1;
        if (kc < 31) {
            an  = *(const v8s*)(ar  + (kc + 1) * 32);
            b0n = *(const v8s*)(b0r + (kc + 1) * 32);
            b1n = *(const v8s*)(b1r + (kc + 1) * 32);
        }
        acc0 = __builtin_amdgcn_mfma_f32_16x16x32_bf16(a, b0, acc0, 0, 0, 0);
        acc1 = __builtin_amdgcn_mfma_f32_16x16x32_bf16(a, b1, acc1, 0, 0, 0);
        a = an; b0 = b0n; b1 = b1n;
    }

    #pragma unroll
    for (int tn = 0; tn < 2; ++tn) {
        int col = wn * 32 + tn * 16 + l15;
        #pragma unroll
        for (int reg = 0; reg < 4; ++reg) {
            int row = wm * 16 + quad * 4 + reg;
            float vv = tn ? acc1[reg] : acc0[reg];
            unsigned short hb = f2bf(vv);
            C[(i0 + row) * N + j0 + col] = hb;
            Lt[row][col] = hb;
        }
    }
    __syncthreads();
    const int c = t >> 3, r0 = (t & 7) * 8;
    uint4 q;
    unsigned short* qq = (unsigned short*)&q;
    #pragma unroll
    for (int e = 0; e < 8; ++e) qq[e] = Lt[r0 + e][c];
    *(uint4*)(CT + (j0 + c) * N + i0 + r0) = q;
}

// ---------------- K5: v[r] = base[r] + (M z)[r], bf16 matrix ----------------
__global__ __launch_bounds__(256) void k_mvb(
    const unsigned short* __restrict__ M, const float* __restrict__ base,
    const float* __restrict__ z, float* __restrict__ v)
{
    const int r = (blockIdx.x * 256 + threadIdx.x) >> 6;
    const int lane = threadIdx.x & 63;
    const uint4* m4 = (const uint4*)(M + r * N + lane * 16);
    const float4* z4 = (const float4*)(z + lane * 16);
    uint4 ma = m4[0], mb = m4[1];
    float4 z0 = z4[0], z1 = z4[1], z2 = z4[2], z3 = z4[3];
    float acc = 0.f;
    acc += bf2f((unsigned short)(ma.x)) * z0.x + bf2f((unsigned short)(ma.x >> 16)) * z0.y;
    acc += bf2f((unsigned short)(ma.y)) * z0.z + bf2f((unsigned short)(ma.y >> 16)) * z0.w;
    acc += bf2f((unsigned short)(ma.z)) * z1.x + bf2f((unsigned short)(ma.z >> 16)) * z1.y;
    acc += bf2f((unsigned short)(ma.w)) * z1.z + bf2f((unsigned short)(ma.w >> 16)) * z1.w;
    acc += bf2f((unsigned short)(mb.x)) * z2.x + bf2f((unsigned short)(mb.x >> 16)) * z2.y;
    acc += bf2f((unsigned short)(mb.y)) * z2.z + bf2f((unsigned short)(mb.y >> 16)) * z2.w;
    acc += bf2f((unsigned short)(mb.z)) * z3.x + bf2f((unsigned short)(mb.z >> 16)) * z3.y;
    acc += bf2f((unsigned short)(mb.w)) * z3.z + bf2f((unsigned short)(mb.w >> 16)) * z3.w;
    #pragma unroll
    for (int off = 32; off >= 1; off >>= 1) acc += __shfl_xor(acc, off, 64);
    if (lane == 0) v[r] = base[r] + acc;
}

// ---------------- K6: epilogue: P=0.1*u; center; relu*100; softmax ----------
__global__ __launch_bounds__(1024) void k_epilogue(const float* __restrict__ uf,
                                                   float* __restrict__ out)
{
    __shared__ float red[16];
    __shared__ float bval;
    const int t = threadIdx.x;
    const int wv = t >> 6, lane = t & 63;
    const bool valid = t < NM1;
    float P = valid ? 0.1f * uf[t + 1] : 0.f;

    float s = P;
    #pragma unroll
    for (int off = 32; off >= 1; off >>= 1) s += __shfl_down(s, off, 64);
    if (lane == 0) red[wv] = s;
    __syncthreads();
    if (t < 64) {
        float s2 = (t < 16) ? red[t] : 0.f;
        #pragma unroll
        for (int off = 8; off >= 1; off >>= 1) s2 += __shfl_down(s2, off, 64);
        if (t == 0) bval = s2 / 1023.0f;
    }
    __syncthreads();
    float mean = bval;
    P = valid ? fmaxf(P - mean, 0.f) * 100.f : 0.f;

    __syncthreads();
    float m = P;
    #pragma unroll
    for (int off = 32; off >= 1; off >>= 1) m = fmaxf(m, __shfl_down(m, off, 64));
    if (lane == 0) red[wv] = m;
    __syncthreads();
    if (t < 64) {
        float m2 = (t < 16) ? red[t] : 0.f;
        #pragma unroll
        for (int off = 8; off >= 1; off >>= 1) m2 = fmaxf(m2, __shfl_down(m2, off, 64));
        if (t == 0) bval = m2;
    }
    __syncthreads();
    float gmax = bval;
    float e = valid ? expf(P - gmax) : 0.f;

    __syncthreads();
    float s3 = e;
    #pragma unroll
    for (int off = 32; off >= 1; off >>= 1) s3 += __shfl_down(s3, off, 64);
    if (lane == 0) red[wv] = s3;
    __syncthreads();
    if (t < 64) {
        float s4 = (t < 16) ? red[t] : 0.f;
        #pragma unroll
        for (int off = 8; off >= 1; off >>= 1) s4 += __shfl_down(s4, off, 64);
        if (t == 0) bval = s4;
    }
    __syncthreads();
    if (valid) out[t] = e / bval;
}

extern "C" void kernel_launch(void* const* d_in, const int* in_sizes, int n_in,
                              void* d_out, int out_size, void* d_ws, size_t ws_size,
                              hipStream_t stream) {
    const float* f  = (const float*)d_in[0];
    const float* w1 = (const float*)d_in[1];
    const float* b1 = (const float*)d_in[2];
    const float* w2 = (const float*)d_in[3];
    const float* b2 = (const float*)d_in[4];
    const float* w3 = (const float*)d_in[5];
    const float* b3 = (const float*)d_in[6];
    const float* w4 = (const float*)d_in[7];
    const float* b4 = (const float*)d_in[8];
    float* ws = (float*)d_ws;

    float* A     = ws;                  // 1048576
    float* C1    = ws + 1048576;        // 16384
    float* Wboth = ws + 1064960;        // 32768
    float* bboth = ws + 1097728;        // 256
    float* beta1 = ws + 1097984;        // 128
    float* fn2   = ws + 1098112;        // 1024
    float* mag   = ws + 1099136;        // 1024
    float* total = ws + 1100160;        // 1024
    float* P0f   = ws + 1101184;        // 1024
    float* t0    = ws + 1102208;        // 1024
    float* t1    = ws + 1103232;        // 1024
    unsigned short* xb  = (unsigned short*)(ws + 1104256);  // 1024x128 bf16
    unsigned short* Bb  = (unsigned short*)(ws + 1169792);  // 1024^2 bf16 each
    unsigned short* BbT = (unsigned short*)(ws + 1694080);
    unsigned short* B2  = (unsigned short*)(ws + 2218368);
    unsigned short* B2T = (unsigned short*)(ws + 2742656);
    unsigned short* B4  = (unsigned short*)(ws + 3266944);
    unsigned short* B4T = (unsigned short*)(ws + 3791232);
    unsigned short* B8  = (unsigned short*)(ws + 4315520);
    unsigned short* B8T = (unsigned short*)(ws + 4839808);
    float* out = (float*)d_out;

    k_init<<<12, 256, 0, stream>>>(fn2);   // zeros fn2, mag, total (contiguous)

    // weight composition: Wboth rows 0-127 = G = W4*W3*W2 ; rows 128-255 = W1*G
    k_small<<<65, 256, 0, stream>>>(w3, w2, b2, b3, C1, beta1);
    k_small<<<65, 256, 0, stream>>>(w4, C1, beta1, b4, Wboth, bboth);
    k_small<<<65, 256, 0, stream>>>(w1, Wboth, bboth, b1, Wboth + 16384, bboth + 128);

    k_gemm<<<dim3(4, 16), 256, 0, stream>>>(f, Wboth, bboth, xb, fn2, mag);
    k_aff<<<dim3(16, 16), 512, 0, stream>>>(xb, mag, fn2, A, total);
    k_makeB<<<dim3(16, 16), 256, 0, stream>>>(A, total, Bb, BbT, P0f);

    k_sq<<<dim3(16, 16), 512, 0, stream>>>(Bb, BbT, B2, B2T);
    k_sq<<<dim3(16, 16), 512, 0, stream>>>(B2, B2T, B4, B4T);
    k_sq<<<dim3(16, 16), 512, 0, stream>>>(B4, B4T, B8, B8T);

    // bracket: z_7 = sum_{k=0}^{7} (B8)^k P0   (7 applications of z <- P0 + B8 z)
    float* zin = P0f;
    float* zout = t0;
    for (int it = 0; it < 7; ++it) {
        k_mvb<<<256, 256, 0, stream>>>(B8, P0f, zin, zout);
        zin = zout;
        zout = (zin == t0) ? t1 : t0;
    }
    // combines: z <- z + B4 z ; z <- z + B2 z ; z <- z + Bb z
    k_mvb<<<256, 256, 0, stream>>>(B4, zin, zin, zout);
    { float* tmp = zin; zin = zout; zout = tmp; }
    k_mvb<<<256, 256, 0, stream>>>(B2, zin, zin, zout);
    { float* tmp = zin; zin = zout; zout = tmp; }
    k_mvb<<<256, 256, 0, stream>>>(Bb, zin, zin, zout);
    { float* tmp = zin; zin = zout; zout = tmp; }

    k_epilogue<<<1, 1024, 0, stream>>>(zin, out);
}